// Round 1
// baseline (1945.650 us; speedup 1.0000x reference)
//
#include <hip/hip_runtime.h>
#include <stdint.h>
#include <stddef.h>

#define DIM_C    384
#define NHEADS   12
#define SEQ      49
#define HEADD    32
#define NWIN     4096
#define MTOT     (NWIN * SEQ)     // 200704
#define QKV_N    (3 * DIM_C)      // 1152
#define ATTN_SCALE 0.17677669529663687f
#define PAD_K    392              // LDS row stride (elems): row-to-row bank shift = 4

typedef __bf16 bf16_t;
typedef __bf16 bf16x8 __attribute__((ext_vector_type(8)));
typedef __bf16 bf16x4 __attribute__((ext_vector_type(4)));
typedef float  f32x4  __attribute__((ext_vector_type(4)));

static_assert(sizeof(bf16x8) == 16, "bf16x8 must be 16B");

#define QKV_BYTES     ((size_t)MTOT * QKV_N * 2)   // 462,422,016
#define AOUT_BYTES    ((size_t)MTOT * DIM_C * 2)   // 154,140,672
#define BIAS_ELEMS    (NHEADS * SEQ * SEQ)         // 28,812
#define BIASF_BYTES   ((size_t)BIAS_ELEMS * 4)     // 115,248
#define QKVW_BF_BYTES ((size_t)QKV_N * DIM_C * 2)  // 884,736

// ---------------------------------------------------------------------------
// Kernel 0: f32 -> bf16 weight conversion (one-time, tiny; keeps GEMM k-loop
// free of conversion VALU and halves weight L2 footprint)
// ---------------------------------------------------------------------------
__global__ void convert_f32_bf16_kernel(const float* __restrict__ src,
                                        bf16_t* __restrict__ dst, int n4) {
    int i = blockIdx.x * 256 + threadIdx.x;
    if (i < n4) {
        float4 v = ((const float4*)src)[i];
        bf16x4 t;
        t[0] = (bf16_t)v.x; t[1] = (bf16_t)v.y;
        t[2] = (bf16_t)v.z; t[3] = (bf16_t)v.w;
        ((bf16x4*)dst)[i] = t;
    }
}

// ---------------------------------------------------------------------------
// Kernel 1: expand bias_table[rel_index] -> bias_full[h][m][n] (f32)
// ---------------------------------------------------------------------------
__global__ void bias_expand_kernel(const float* __restrict__ table,
                                   const int* __restrict__ rel,
                                   float* __restrict__ bias_full) {
    int i = blockIdx.x * 256 + threadIdx.x;
    if (i < BIAS_ELEMS) {
        int h  = i / (SEQ * SEQ);
        int mn = i % (SEQ * SEQ);
        bias_full[i] = table[rel[mn] * NHEADS + h];
    }
}

// ---------------------------------------------------------------------------
// Kernel 2/4: full-K M-slab GEMM. One block = 128 rows x all N cols.
// A staged ONCE in LDS (K=384 full, bf16), then in-block loop over N-tiles.
// B = pre-converted bf16 weights [N,384], frags read direct from global
// (L1/L2-resident, 8KB slab per k-step) -> no inner syncs, no re-fetch of A.
// C[m,n] = sum_k A[m,k]*B[n,k] + bias[n].
// ---------------------------------------------------------------------------
template <bool A_BF16, bool OUT_BF16, int NT>
__global__ __launch_bounds__(512) void gemm_fullk_kernel(
    const void* __restrict__ Av, const bf16_t* __restrict__ Bw,
    const float* __restrict__ bias, void* __restrict__ Cv, int ldc) {
    __shared__ bf16_t As[128 * PAD_K];   // 100,352 B -> 1 block/CU, 8 waves

    const int tid  = threadIdx.x;
    const int lane = tid & 63;
    const int wave = tid >> 6;           // 0..7
    const int l15  = lane & 15;
    const int quad = lane >> 4;
    const int wm   = (wave & 3) * 32;    // wave row offset (4 groups x 32 rows)
    const int wn   = (wave >> 2) * 64;   // wave col offset within 128-wide N-tile
    const size_t m0 = (size_t)blockIdx.x * 128;

    // ---- stage A once: 128 rows x 384 k (4 threads/row, interleaved chunks) ----
    {
        const int row = tid >> 2;
        bf16_t* dst = &As[row * PAD_K];
        if constexpr (A_BF16) {
            const bf16_t* src = (const bf16_t*)Av + (m0 + row) * DIM_C;
#pragma unroll
            for (int i = 0; i < 12; i++) {
                int c = (tid & 3) + i * 4;            // 48 chunks of 8 bf16/row
                *(bf16x8*)(dst + c * 8) = *(const bf16x8*)(src + c * 8);
            }
        } else {
            const float* src = (const float*)Av + (m0 + row) * DIM_C;
#pragma unroll
            for (int i = 0; i < 24; i++) {
                int c = (tid & 3) + i * 4;            // 96 chunks of 4 f32/row
                float4 v = *(const float4*)(src + c * 4);
                bf16x4 t;
                t[0] = (bf16_t)v.x; t[1] = (bf16_t)v.y;
                t[2] = (bf16_t)v.z; t[3] = (bf16_t)v.w;
                *(bf16x4*)(dst + c * 4) = t;
            }
        }
    }
    __syncthreads();   // the ONLY barrier; A is read-only afterwards

#pragma unroll 1
    for (int ni = 0; ni < NT; ++ni) {
        const int n0 = ni * 128;
        f32x4 acc[2][4];
#pragma unroll
        for (int mi = 0; mi < 2; mi++)
#pragma unroll
            for (int nj = 0; nj < 4; nj++) acc[mi][nj] = f32x4{0.f, 0.f, 0.f, 0.f};

#pragma unroll
        for (int kt = 0; kt < DIM_C / 32; ++kt) {
            bf16x8 af[2], bfr[4];
#pragma unroll
            for (int mi = 0; mi < 2; mi++)
                af[mi] = *(const bf16x8*)(&As[(wm + mi * 16 + l15) * PAD_K + kt * 32 + quad * 8]);
#pragma unroll
            for (int nj = 0; nj < 4; nj++)
                bfr[nj] = *(const bf16x8*)(Bw + (size_t)(n0 + wn + nj * 16 + l15) * DIM_C + kt * 32 + quad * 8);
#pragma unroll
            for (int mi = 0; mi < 2; mi++)
#pragma unroll
                for (int nj = 0; nj < 4; nj++)
                    acc[mi][nj] = __builtin_amdgcn_mfma_f32_16x16x32_bf16(
                        af[mi], bfr[nj], acc[mi][nj], 0, 0, 0);
        }

        // ---- epilogue: C/D layout col=lane&15, row=quad*4+reg ----
#pragma unroll
        for (int nj = 0; nj < 4; nj++) {
            const int col = n0 + wn + nj * 16 + l15;
            const float bc = bias[col];
#pragma unroll
            for (int mi = 0; mi < 2; mi++)
#pragma unroll
                for (int r = 0; r < 4; r++) {
                    const size_t row = m0 + wm + mi * 16 + quad * 4 + r;
                    float v = acc[mi][nj][r] + bc;
                    if constexpr (OUT_BF16)
                        ((bf16_t*)Cv)[row * (size_t)ldc + col] = (bf16_t)v;
                    else
                        ((float*)Cv)[row * (size_t)ldc + col] = v;
                }
        }
    }
}

// ---------------------------------------------------------------------------
// Kernel 3: fused window attention. 1 block / window, 1 wave handles 3 heads.
// qkv row-major [MTOT, 1152]; q cols h*32, k cols 384+h*32, v cols 768+h*32.
// (unchanged this round)
// ---------------------------------------------------------------------------
__global__ __launch_bounds__(256) void attn_kernel(
    const bf16_t* __restrict__ qkv, const float* __restrict__ bias_full,
    bf16_t* __restrict__ aout) {
    // per-wave P scratch: 64 rows x stride 72 elems (144 B: 16B-aligned b128 reads)
    __shared__ bf16_t Ps[4][64 * 72];

    const int b    = blockIdx.x;
    const int lane = threadIdx.x & 63;
    const int wave = threadIdx.x >> 6;
    const int l15  = lane & 15;
    const int quad = lane >> 4;
    const bf16_t* base = qkv + (size_t)b * SEQ * QKV_N;
    bf16_t* ps = &Ps[wave][0];

#pragma unroll 1
    for (int hi = 0; hi < 3; ++hi) {
        const int h = wave * 3 + hi;
        // ---- Q/K fragments straight from global (A/B frag = 8 contiguous k) ----
        bf16x8 qf[4], kf[4];
#pragma unroll
        for (int mi = 0; mi < 4; mi++) {
            int row = mi * 16 + l15;
            if (row < SEQ) {
                qf[mi] = *(const bf16x8*)(base + (size_t)row * QKV_N + h * HEADD + quad * 8);
                kf[mi] = *(const bf16x8*)(base + (size_t)row * QKV_N + DIM_C + h * HEADD + quad * 8);
            } else {
                bf16x8 z;
#pragma unroll
                for (int j = 0; j < 8; j++) z[j] = (bf16_t)0.f;
                qf[mi] = z; kf[mi] = z;
            }
        }
        // ---- S = Q K^T (64x64 padded) ----
        f32x4 S[4][4];
#pragma unroll
        for (int mi = 0; mi < 4; mi++)
#pragma unroll
            for (int ni = 0; ni < 4; ni++)
                S[mi][ni] = __builtin_amdgcn_mfma_f32_16x16x32_bf16(
                    qf[mi], kf[ni], f32x4{0.f, 0.f, 0.f, 0.f}, 0, 0, 0);
        // ---- scale + bias + mask (C layout: m = mi*16+quad*4+r, n = ni*16+l15) ----
        const float* bh = bias_full + h * SEQ * SEQ;
#pragma unroll
        for (int mi = 0; mi < 4; mi++)
#pragma unroll
            for (int r = 0; r < 4; r++) {
                int m = mi * 16 + quad * 4 + r;
#pragma unroll
                for (int ni = 0; ni < 4; ni++) {
                    int n = ni * 16 + l15;
                    float s = S[mi][ni][r];
                    s = (m < SEQ && n < SEQ) ? s * ATTN_SCALE + bh[m * SEQ + n] : -1e30f;
                    S[mi][ni][r] = s;
                }
            }
        // ---- row softmax: reduce across the 16 lanes of each quad-group ----
#pragma unroll
        for (int mi = 0; mi < 4; mi++)
#pragma unroll
            for (int r = 0; r < 4; r++) {
                float mx = -1e30f;
#pragma unroll
                for (int ni = 0; ni < 4; ni++) mx = fmaxf(mx, S[mi][ni][r]);
#pragma unroll
                for (int off = 1; off < 16; off <<= 1)
                    mx = fmaxf(mx, __shfl_xor(mx, off, 64));
                float sum = 0.f;
#pragma unroll
                for (int ni = 0; ni < 4; ni++) {
                    float e = __expf(S[mi][ni][r] - mx);
                    S[mi][ni][r] = e;
                    sum += e;
                }
#pragma unroll
                for (int off = 1; off < 16; off <<= 1)
                    sum += __shfl_xor(sum, off, 64);
                float inv = 1.f / sum;
                int m = mi * 16 + quad * 4 + r;
#pragma unroll
                for (int ni = 0; ni < 4; ni++) {
                    int n = ni * 16 + l15;
                    ps[m * 72 + n] = (bf16_t)(S[mi][ni][r] * inv);
                }
            }
        // ---- V fragments: B[k][d], k strided rows (guarded), d contiguous lanes ----
        bf16x8 vf[2][2];
#pragma unroll
        for (int ki = 0; ki < 2; ki++)
#pragma unroll
            for (int di = 0; di < 2; di++) {
#pragma unroll
                for (int j = 0; j < 8; j++) {
                    int k = ki * 32 + quad * 8 + j;
                    vf[ki][di][j] = (k < SEQ)
                        ? base[(size_t)k * QKV_N + 2 * DIM_C + h * HEADD + di * 16 + l15]
                        : (bf16_t)0.f;
                }
            }
        // ---- O = P V  (P A-frags from LDS) ----
        f32x4 O[4][2];
#pragma unroll
        for (int mi = 0; mi < 4; mi++)
#pragma unroll
            for (int di = 0; di < 2; di++) O[mi][di] = f32x4{0.f, 0.f, 0.f, 0.f};
#pragma unroll
        for (int mi = 0; mi < 4; mi++)
#pragma unroll
            for (int ki = 0; ki < 2; ki++) {
                bf16x8 pa = *(const bf16x8*)(ps + (mi * 16 + l15) * 72 + ki * 32 + quad * 8);
#pragma unroll
                for (int di = 0; di < 2; di++)
                    O[mi][di] = __builtin_amdgcn_mfma_f32_16x16x32_bf16(
                        pa, vf[ki][di], O[mi][di], 0, 0, 0);
            }
        // ---- store O rows m<49, layout [b*49+m, h*32+d] ----
#pragma unroll
        for (int mi = 0; mi < 4; mi++)
#pragma unroll
            for (int di = 0; di < 2; di++)
#pragma unroll
                for (int r = 0; r < 4; r++) {
                    int m = mi * 16 + quad * 4 + r;
                    if (m < SEQ)
                        aout[((size_t)b * SEQ + m) * DIM_C + h * HEADD + di * 16 + l15] =
                            (bf16_t)O[mi][di][r];
                }
    }
}

// ---------------------------------------------------------------------------
extern "C" void kernel_launch(void* const* d_in, const int* in_sizes, int n_in,
                              void* d_out, int out_size, void* d_ws, size_t ws_size,
                              hipStream_t stream) {
    (void)in_sizes; (void)n_in; (void)out_size; (void)ws_size;
    const float* x      = (const float*)d_in[0];
    const float* qkv_w  = (const float*)d_in[1];
    const float* qkv_b  = (const float*)d_in[2];
    const float* proj_w = (const float*)d_in[3];
    const float* proj_b = (const float*)d_in[4];
    const float* btable = (const float*)d_in[5];
    const int*   rel    = (const int*)d_in[6];
    float* out = (float*)d_out;

    char* ws = (char*)d_ws;
    bf16_t* qkv        = (bf16_t*)ws;
    bf16_t* aout       = (bf16_t*)(ws + QKV_BYTES);
    float*  bias_full  = (float*)(ws + QKV_BYTES + AOUT_BYTES);
    bf16_t* qkv_w_bf   = (bf16_t*)(ws + QKV_BYTES + AOUT_BYTES + BIASF_BYTES);
    bf16_t* proj_w_bf  = (bf16_t*)(ws + QKV_BYTES + AOUT_BYTES + BIASF_BYTES + QKVW_BF_BYTES);

    // one-time small preprocessing
    convert_f32_bf16_kernel<<<(QKV_N * DIM_C / 4 + 255) / 256, 256, 0, stream>>>(
        qkv_w, qkv_w_bf, QKV_N * DIM_C / 4);
    convert_f32_bf16_kernel<<<(DIM_C * DIM_C / 4 + 255) / 256, 256, 0, stream>>>(
        proj_w, proj_w_bf, DIM_C * DIM_C / 4);
    bias_expand_kernel<<<(BIAS_ELEMS + 255) / 256, 256, 0, stream>>>(btable, rel, bias_full);

    // QKV GEMM: [200704,384] f32 x [1152,384] -> bf16 [200704,1152]
    gemm_fullk_kernel<false, true, QKV_N / 128><<<MTOT / 128, 512, 0, stream>>>(
        x, qkv_w_bf, qkv_b, qkv, QKV_N);
    attn_kernel<<<NWIN, 256, 0, stream>>>(qkv, bias_full, aout);
    // proj GEMM: [200704,384] bf16 x [384,384] -> f32 [200704,384]
    gemm_fullk_kernel<true, false, DIM_C / 128><<<MTOT / 128, 512, 0, stream>>>(
        aout, proj_w_bf, proj_b, out, DIM_C);
}

// Round 2
// 1476.135 us; speedup vs baseline: 1.3181x; 1.3181x over previous
//
#include <hip/hip_runtime.h>
#include <stdint.h>
#include <stddef.h>

#define DIM_C    384
#define NHEADS   12
#define SEQ      49
#define HEADD    32
#define NWIN     4096
#define MTOT     (NWIN * SEQ)     // 200704
#define QKV_N    (3 * DIM_C)      // 1152
#define ATTN_SCALE 0.17677669529663687f

typedef __bf16 bf16_t;
typedef __bf16 bf16x8 __attribute__((ext_vector_type(8)));
typedef __bf16 bf16x4 __attribute__((ext_vector_type(4)));
typedef float  f32x4  __attribute__((ext_vector_type(4)));

static_assert(sizeof(bf16x8) == 16, "bf16x8 must be 16B");

#define QKV_BYTES     ((size_t)MTOT * QKV_N * 2)   // 462,422,016
#define AOUT_BYTES    ((size_t)MTOT * DIM_C * 2)   // 154,140,672
#define BIAS_ELEMS    (NHEADS * SEQ * SEQ)         // 28,812
#define BIASF_BYTES   ((size_t)BIAS_ELEMS * 4)     // 115,248
#define QKVW_BF_BYTES ((size_t)QKV_N * DIM_C * 2)  // 884,736

// ---------------------------------------------------------------------------
// Kernel 0: f32 -> bf16 weight conversion (one-time, tiny). Removes per-k-step
// conversion VALU from the GEMM hot loop; weights stay L2-resident (884 KB).
// ---------------------------------------------------------------------------
__global__ void convert_f32_bf16_kernel(const float* __restrict__ src,
                                        bf16_t* __restrict__ dst, int n4) {
    int i = blockIdx.x * 256 + threadIdx.x;
    if (i < n4) {
        float4 v = ((const float4*)src)[i];
        bf16x4 t;
        t[0] = (bf16_t)v.x; t[1] = (bf16_t)v.y;
        t[2] = (bf16_t)v.z; t[3] = (bf16_t)v.w;
        ((bf16x4*)dst)[i] = t;
    }
}

// ---------------------------------------------------------------------------
// Kernel 1: expand bias_table[rel_index] -> bias_full[h][m][n] (f32)
// ---------------------------------------------------------------------------
__global__ void bias_expand_kernel(const float* __restrict__ table,
                                   const int* __restrict__ rel,
                                   float* __restrict__ bias_full) {
    int i = blockIdx.x * 256 + threadIdx.x;
    if (i < BIAS_ELEMS) {
        int h  = i / (SEQ * SEQ);
        int mn = i % (SEQ * SEQ);
        bias_full[i] = table[rel[mn] * NHEADS + h];
    }
}

// ---------------------------------------------------------------------------
// Kernel 2/4: 128x128 tile MFMA GEMM (round-0 proven structure: 20KB LDS,
// ~35% occupancy, sustains ~3.8 TB/s issue) + XCD-bijective grid swizzle.
//
// Grid is 1D, nwg = (M/128)*NT, nwg%8==0 and (nwg/8)%NT==0, so each XCD owns
// a contiguous range of M-slabs with ALL N-tiles (N innermost): the 196KB
// A-slab is fetched from HBM once per XCD and L2-hits for the other NT-1
// blocks. B weights are pre-converted bf16 (staging = pure vector copy).
// C[m,n] = sum_k A[m,k]*B[n,k] + bias[n].
// ---------------------------------------------------------------------------
template <bool A_BF16, bool OUT_BF16, int NT>
__global__ __launch_bounds__(256) void gemm_kernel(
    const void* __restrict__ Av, const bf16_t* __restrict__ Bw,
    const float* __restrict__ bias, void* __restrict__ Cv, int ldc) {
    // LDS tiles, padded row stride 40 elems (80 B) -> 16B-aligned b128 frag reads
    __shared__ bf16_t As[128 * 40];
    __shared__ bf16_t Bs[128 * 40];

    const int tid  = threadIdx.x;
    const int lane = tid & 63;
    const int wave = tid >> 6;
    const int l15  = lane & 15;
    const int quad = lane >> 4;
    const int wm = (wave >> 1) * 64;   // wave row offset in tile
    const int wn = (wave & 1) * 64;    // wave col offset in tile

    // ---- XCD-aware swizzle: bid -> (bm, bn), N innermost per XCD chunk ----
    const int cpx = gridDim.x >> 3;          // nwg/8, exact
    const int bid = blockIdx.x;
    const int wid = (bid & 7) * cpx + (bid >> 3);
    const size_t m0 = (size_t)(wid / NT) * 128;
    const int    n0 = (wid % NT) * 128;

    f32x4 acc[4][4];
#pragma unroll
    for (int i = 0; i < 4; i++)
#pragma unroll
        for (int j = 0; j < 4; j++) acc[i][j] = f32x4{0.f, 0.f, 0.f, 0.f};

    for (int kt = 0; kt < DIM_C / 32; ++kt) {
        const int k0 = kt * 32;
        __syncthreads();
        // ---- stage A tile: 128 rows x 32 k ----
        if constexpr (A_BF16) {
            const bf16_t* A = (const bf16_t*)Av;
#pragma unroll
            for (int i = 0; i < 2; i++) {
                int c = tid + i * 256;        // 512 chunks of 8 bf16
                int row = c >> 2, kq = c & 3;
                bf16x8 v = *(const bf16x8*)(A + (m0 + row) * DIM_C + k0 + kq * 8);
                *(bf16x8*)(&As[row * 40 + kq * 8]) = v;
            }
        } else {
            const float* A = (const float*)Av;
#pragma unroll
            for (int i = 0; i < 4; i++) {
                int c = tid + i * 256;        // 1024 chunks of 4 f32
                int row = c >> 3, kq = c & 7;
                float4 v = *(const float4*)(A + (m0 + row) * DIM_C + k0 + kq * 4);
                bf16x4 t;
                t[0] = (bf16_t)v.x; t[1] = (bf16_t)v.y;
                t[2] = (bf16_t)v.z; t[3] = (bf16_t)v.w;
                *(bf16x4*)(&As[row * 40 + kq * 4]) = t;
            }
        }
        // ---- stage B tile (bf16 weights: pure vector copy) ----
        {
#pragma unroll
            for (int i = 0; i < 2; i++) {
                int c = tid + i * 256;        // 512 chunks of 8 bf16
                int row = c >> 2, kq = c & 3;
                bf16x8 v = *(const bf16x8*)(Bw + (size_t)(n0 + row) * DIM_C + k0 + kq * 8);
                *(bf16x8*)(&Bs[row * 40 + kq * 8]) = v;
            }
        }
        __syncthreads();
        // ---- fragments + MFMA ----
        bf16x8 af[4], bfr[4];
#pragma unroll
        for (int mi = 0; mi < 4; mi++)
            af[mi] = *(const bf16x8*)(&As[(wm + mi * 16 + l15) * 40 + quad * 8]);
#pragma unroll
        for (int ni = 0; ni < 4; ni++)
            bfr[ni] = *(const bf16x8*)(&Bs[(wn + ni * 16 + l15) * 40 + quad * 8]);
#pragma unroll
        for (int mi = 0; mi < 4; mi++)
#pragma unroll
            for (int ni = 0; ni < 4; ni++)
                acc[mi][ni] = __builtin_amdgcn_mfma_f32_16x16x32_bf16(
                    af[mi], bfr[ni], acc[mi][ni], 0, 0, 0);
    }
    // ---- epilogue: C/D layout col=lane&15, row=quad*4+reg ----
#pragma unroll
    for (int mi = 0; mi < 4; mi++) {
#pragma unroll
        for (int ni = 0; ni < 4; ni++) {
            int col = n0 + wn + ni * 16 + l15;
            float bc = bias[col];
#pragma unroll
            for (int r = 0; r < 4; r++) {
                size_t row = m0 + wm + mi * 16 + quad * 4 + r;
                float v = acc[mi][ni][r] + bc;
                if constexpr (OUT_BF16)
                    ((bf16_t*)Cv)[row * (size_t)ldc + col] = (bf16_t)v;
                else
                    ((float*)Cv)[row * (size_t)ldc + col] = v;
            }
        }
    }
}

// ---------------------------------------------------------------------------
// Kernel 3: fused window attention. 1 block / window, 1 wave handles 3 heads.
// qkv row-major [MTOT, 1152]; q cols h*32, k cols 384+h*32, v cols 768+h*32.
// (unchanged this round — want its counters in top-5 next)
// ---------------------------------------------------------------------------
__global__ __launch_bounds__(256) void attn_kernel(
    const bf16_t* __restrict__ qkv, const float* __restrict__ bias_full,
    bf16_t* __restrict__ aout) {
    // per-wave P scratch: 64 rows x stride 72 elems (144 B: 16B-aligned b128 reads)
    __shared__ bf16_t Ps[4][64 * 72];

    const int b    = blockIdx.x;
    const int lane = threadIdx.x & 63;
    const int wave = threadIdx.x >> 6;
    const int l15  = lane & 15;
    const int quad = lane >> 4;
    const bf16_t* base = qkv + (size_t)b * SEQ * QKV_N;
    bf16_t* ps = &Ps[wave][0];

#pragma unroll 1
    for (int hi = 0; hi < 3; ++hi) {
        const int h = wave * 3 + hi;
        // ---- Q/K fragments straight from global (A/B frag = 8 contiguous k) ----
        bf16x8 qf[4], kf[4];
#pragma unroll
        for (int mi = 0; mi < 4; mi++) {
            int row = mi * 16 + l15;
            if (row < SEQ) {
                qf[mi] = *(const bf16x8*)(base + (size_t)row * QKV_N + h * HEADD + quad * 8);
                kf[mi] = *(const bf16x8*)(base + (size_t)row * QKV_N + DIM_C + h * HEADD + quad * 8);
            } else {
                bf16x8 z;
#pragma unroll
                for (int j = 0; j < 8; j++) z[j] = (bf16_t)0.f;
                qf[mi] = z; kf[mi] = z;
            }
        }
        // ---- S = Q K^T (64x64 padded) ----
        f32x4 S[4][4];
#pragma unroll
        for (int mi = 0; mi < 4; mi++)
#pragma unroll
            for (int ni = 0; ni < 4; ni++)
                S[mi][ni] = __builtin_amdgcn_mfma_f32_16x16x32_bf16(
                    qf[mi], kf[ni], f32x4{0.f, 0.f, 0.f, 0.f}, 0, 0, 0);
        // ---- scale + bias + mask (C layout: m = mi*16+quad*4+r, n = ni*16+l15) ----
        const float* bh = bias_full + h * SEQ * SEQ;
#pragma unroll
        for (int mi = 0; mi < 4; mi++)
#pragma unroll
            for (int r = 0; r < 4; r++) {
                int m = mi * 16 + quad * 4 + r;
#pragma unroll
                for (int ni = 0; ni < 4; ni++) {
                    int n = ni * 16 + l15;
                    float s = S[mi][ni][r];
                    s = (m < SEQ && n < SEQ) ? s * ATTN_SCALE + bh[m * SEQ + n] : -1e30f;
                    S[mi][ni][r] = s;
                }
            }
        // ---- row softmax: reduce across the 16 lanes of each quad-group ----
#pragma unroll
        for (int mi = 0; mi < 4; mi++)
#pragma unroll
            for (int r = 0; r < 4; r++) {
                float mx = -1e30f;
#pragma unroll
                for (int ni = 0; ni < 4; ni++) mx = fmaxf(mx, S[mi][ni][r]);
#pragma unroll
                for (int off = 1; off < 16; off <<= 1)
                    mx = fmaxf(mx, __shfl_xor(mx, off, 64));
                float sum = 0.f;
#pragma unroll
                for (int ni = 0; ni < 4; ni++) {
                    float e = __expf(S[mi][ni][r] - mx);
                    S[mi][ni][r] = e;
                    sum += e;
                }
#pragma unroll
                for (int off = 1; off < 16; off <<= 1)
                    sum += __shfl_xor(sum, off, 64);
                float inv = 1.f / sum;
                int m = mi * 16 + quad * 4 + r;
#pragma unroll
                for (int ni = 0; ni < 4; ni++) {
                    int n = ni * 16 + l15;
                    ps[m * 72 + n] = (bf16_t)(S[mi][ni][r] * inv);
                }
            }
        // ---- V fragments: B[k][d], k strided rows (guarded), d contiguous lanes ----
        bf16x8 vf[2][2];
#pragma unroll
        for (int ki = 0; ki < 2; ki++)
#pragma unroll
            for (int di = 0; di < 2; di++) {
#pragma unroll
                for (int j = 0; j < 8; j++) {
                    int k = ki * 32 + quad * 8 + j;
                    vf[ki][di][j] = (k < SEQ)
                        ? base[(size_t)k * QKV_N + 2 * DIM_C + h * HEADD + di * 16 + l15]
                        : (bf16_t)0.f;
                }
            }
        // ---- O = P V  (P A-frags from LDS) ----
        f32x4 O[4][2];
#pragma unroll
        for (int mi = 0; mi < 4; mi++)
#pragma unroll
            for (int di = 0; di < 2; di++) O[mi][di] = f32x4{0.f, 0.f, 0.f, 0.f};
#pragma unroll
        for (int mi = 0; mi < 4; mi++)
#pragma unroll
            for (int ki = 0; ki < 2; ki++) {
                bf16x8 pa = *(const bf16x8*)(ps + (mi * 16 + l15) * 72 + ki * 32 + quad * 8);
#pragma unroll
                for (int di = 0; di < 2; di++)
                    O[mi][di] = __builtin_amdgcn_mfma_f32_16x16x32_bf16(
                        pa, vf[ki][di], O[mi][di], 0, 0, 0);
            }
        // ---- store O rows m<49, layout [b*49+m, h*32+d] ----
#pragma unroll
        for (int mi = 0; mi < 4; mi++)
#pragma unroll
            for (int di = 0; di < 2; di++)
#pragma unroll
                for (int r = 0; r < 4; r++) {
                    int m = mi * 16 + quad * 4 + r;
                    if (m < SEQ)
                        aout[((size_t)b * SEQ + m) * DIM_C + h * HEADD + di * 16 + l15] =
                            (bf16_t)O[mi][di][r];
                }
    }
}

// ---------------------------------------------------------------------------
extern "C" void kernel_launch(void* const* d_in, const int* in_sizes, int n_in,
                              void* d_out, int out_size, void* d_ws, size_t ws_size,
                              hipStream_t stream) {
    (void)in_sizes; (void)n_in; (void)out_size; (void)ws_size;
    const float* x      = (const float*)d_in[0];
    const float* qkv_w  = (const float*)d_in[1];
    const float* qkv_b  = (const float*)d_in[2];
    const float* proj_w = (const float*)d_in[3];
    const float* proj_b = (const float*)d_in[4];
    const float* btable = (const float*)d_in[5];
    const int*   rel    = (const int*)d_in[6];
    float* out = (float*)d_out;

    char* ws = (char*)d_ws;
    bf16_t* qkv        = (bf16_t*)ws;
    bf16_t* aout       = (bf16_t*)(ws + QKV_BYTES);
    float*  bias_full  = (float*)(ws + QKV_BYTES + AOUT_BYTES);
    bf16_t* qkv_w_bf   = (bf16_t*)(ws + QKV_BYTES + AOUT_BYTES + BIASF_BYTES);
    bf16_t* proj_w_bf  = (bf16_t*)(ws + QKV_BYTES + AOUT_BYTES + BIASF_BYTES + QKVW_BF_BYTES);

    // one-time small preprocessing
    convert_f32_bf16_kernel<<<(QKV_N * DIM_C / 4 + 255) / 256, 256, 0, stream>>>(
        qkv_w, qkv_w_bf, QKV_N * DIM_C / 4);
    convert_f32_bf16_kernel<<<(DIM_C * DIM_C / 4 + 255) / 256, 256, 0, stream>>>(
        proj_w, proj_w_bf, DIM_C * DIM_C / 4);
    bias_expand_kernel<<<(BIAS_ELEMS + 255) / 256, 256, 0, stream>>>(btable, rel, bias_full);

    // QKV GEMM: [200704,384] f32 x bf16 W[1152,384] -> bf16 [200704,1152]
    // nwg = 1568*9 = 14112 (%8==0, chunk 1764 = 196*9: exact XCD ownership)
    gemm_kernel<false, true, QKV_N / 128><<<(MTOT / 128) * (QKV_N / 128), 256, 0, stream>>>(
        x, qkv_w_bf, qkv_b, qkv, QKV_N);
    attn_kernel<<<NWIN, 256, 0, stream>>>(qkv, bias_full, aout);
    // proj GEMM: [200704,384] bf16 x bf16 W[384,384] -> f32 [200704,384]
    // nwg = 1568*3 = 4704 (%8==0, chunk 588 = 196*3)
    gemm_kernel<true, false, DIM_C / 128><<<(MTOT / 128) * (DIM_C / 128), 256, 0, stream>>>(
        aout, proj_w_bf, proj_b, out, DIM_C);
}

// Round 4
// 1330.093 us; speedup vs baseline: 1.4628x; 1.1098x over previous
//
#include <hip/hip_runtime.h>
#include <stdint.h>
#include <stddef.h>

#define DIM_C    384
#define NHEADS   12
#define SEQ      49
#define HEADD    32
#define NWIN     4096
#define MTOT     (NWIN * SEQ)     // 200704
#define QKV_N    (3 * DIM_C)      // 1152
#define ATTN_SCALE 0.17677669529663687f

typedef __bf16 bf16_t;
typedef __bf16 bf16x8 __attribute__((ext_vector_type(8)));
typedef __bf16 bf16x4 __attribute__((ext_vector_type(4)));
typedef float  f32x4  __attribute__((ext_vector_type(4)));

static_assert(sizeof(bf16x8) == 16, "bf16x8 must be 16B");

// workspace layout (vt lives in d_out -> ws stays under the proven ~618MB)
#define QK_BYTES      ((size_t)MTOT * 768 * 2)          // 308,281,344
#define VT_BYTES      ((size_t)NWIN * 384 * 64 * 2)     // 201,326,592 (in d_out, 308MB)
#define AOUT_BYTES    ((size_t)MTOT * DIM_C * 2)        // 154,140,672
#define BIASL_BYTES   ((size_t)NHEADS * 64 * 64 * 4)    // 196,608
#define QKVW_BF_BYTES ((size_t)QKV_N * DIM_C * 2)       // 884,736

// ---------------------------------------------------------------------------
// Kernel 0: f32 -> bf16 weight conversion (one-time, tiny)
// ---------------------------------------------------------------------------
__global__ void convert_f32_bf16_kernel(const float* __restrict__ src,
                                        bf16_t* __restrict__ dst, int n4) {
    int i = blockIdx.x * 256 + threadIdx.x;
    if (i < n4) {
        float4 v = ((const float4*)src)[i];
        bf16x4 t;
        t[0] = (bf16_t)v.x; t[1] = (bf16_t)v.y;
        t[2] = (bf16_t)v.z; t[3] = (bf16_t)v.w;
        ((bf16x4*)dst)[i] = t;
    }
}

// ---------------------------------------------------------------------------
// Kernel 1: bias -> lane-friendly padded layout bias_l[h][m:64][l15:16][ni:4]
// value at (h, m, n=ni*16+l15) = table[rel[m*49+n]*12+h] for m,n<49 else -1e30
// (padding folds the mask into the bias: S*scale + (-1e30) -> exp -> 0)
// ---------------------------------------------------------------------------
__global__ void bias_expand_kernel(const float* __restrict__ table,
                                   const int* __restrict__ rel,
                                   float* __restrict__ bias_l) {
    int i = blockIdx.x * 256 + threadIdx.x;   // over 12*64*64 = 49152
    if (i < NHEADS * 64 * 64) {
        int h  = i >> 12;
        int mn = i & 4095;
        int m = mn >> 6, n = mn & 63;
        float v = -1e30f;
        if (m < SEQ && n < SEQ) v = table[rel[m * SEQ + n] * NHEADS + h];
        int l = n & 15, ni = n >> 4;
        bias_l[((h * 64 + m) * 16 + l) * 4 + ni] = v;
    }
}

// ---------------------------------------------------------------------------
// Kernel 2/4: 128x128 tile MFMA GEMM + XCD-bijective swizzle (N innermost).
// MODE 0: plain f32 output (proj).
// MODE 1: QKV split output: tiles n0<768 -> bf16 qk[row][768];
//         tiles n0>=768 -> V^T vt[b][vcol:384][s:64] (s-padding zeroed here).
// C[m,n] = sum_k A[m,k]*B[n,k] + bias[n].
// ---------------------------------------------------------------------------
template <bool A_BF16, int MODE, int NT>
__global__ __launch_bounds__(256) void gemm_kernel(
    const void* __restrict__ Av, const bf16_t* __restrict__ Bw,
    const float* __restrict__ bias, void* __restrict__ C0,
    bf16_t* __restrict__ vt, int ldc) {
    __shared__ bf16_t As[128 * 40];
    __shared__ bf16_t Bs[128 * 40];

    const int tid  = threadIdx.x;
    const int lane = tid & 63;
    const int wave = tid >> 6;
    const int l15  = lane & 15;
    const int quad = lane >> 4;
    const int wm = (wave >> 1) * 64;
    const int wn = (wave & 1) * 64;

    // XCD-aware swizzle: nwg%8==0 and (nwg/8)%NT==0 by construction
    const int cpx = gridDim.x >> 3;
    const int bid = blockIdx.x;
    const int wid = (bid & 7) * cpx + (bid >> 3);
    const size_t m0 = (size_t)(wid / NT) * 128;
    const int    n0 = (wid % NT) * 128;

    f32x4 acc[4][4];
#pragma unroll
    for (int i = 0; i < 4; i++)
#pragma unroll
        for (int j = 0; j < 4; j++) acc[i][j] = f32x4{0.f, 0.f, 0.f, 0.f};

    for (int kt = 0; kt < DIM_C / 32; ++kt) {
        const int k0 = kt * 32;
        __syncthreads();
        if constexpr (A_BF16) {
            const bf16_t* A = (const bf16_t*)Av;
#pragma unroll
            for (int i = 0; i < 2; i++) {
                int c = tid + i * 256;
                int row = c >> 2, kq = c & 3;
                bf16x8 v = *(const bf16x8*)(A + (m0 + row) * DIM_C + k0 + kq * 8);
                *(bf16x8*)(&As[row * 40 + kq * 8]) = v;
            }
        } else {
            const float* A = (const float*)Av;
#pragma unroll
            for (int i = 0; i < 4; i++) {
                int c = tid + i * 256;
                int row = c >> 3, kq = c & 7;
                float4 v = *(const float4*)(A + (m0 + row) * DIM_C + k0 + kq * 4);
                bf16x4 t;
                t[0] = (bf16_t)v.x; t[1] = (bf16_t)v.y;
                t[2] = (bf16_t)v.z; t[3] = (bf16_t)v.w;
                *(bf16x4*)(&As[row * 40 + kq * 4]) = t;
            }
        }
        {
#pragma unroll
            for (int i = 0; i < 2; i++) {
                int c = tid + i * 256;
                int row = c >> 2, kq = c & 3;
                bf16x8 v = *(const bf16x8*)(Bw + (size_t)(n0 + row) * DIM_C + k0 + kq * 8);
                *(bf16x8*)(&Bs[row * 40 + kq * 8]) = v;
            }
        }
        __syncthreads();
        bf16x8 af[4], bfr[4];
#pragma unroll
        for (int mi = 0; mi < 4; mi++)
            af[mi] = *(const bf16x8*)(&As[(wm + mi * 16 + l15) * 40 + quad * 8]);
#pragma unroll
        for (int ni = 0; ni < 4; ni++)
            bfr[ni] = *(const bf16x8*)(&Bs[(wn + ni * 16 + l15) * 40 + quad * 8]);
#pragma unroll
        for (int mi = 0; mi < 4; mi++)
#pragma unroll
            for (int ni = 0; ni < 4; ni++)
                acc[mi][ni] = __builtin_amdgcn_mfma_f32_16x16x32_bf16(
                    af[mi], bfr[ni], acc[mi][ni], 0, 0, 0);
    }

    // ---- epilogue: C/D layout col=lane&15, row=quad*4+reg ----
    if constexpr (MODE == 0) {
        float* C = (float*)C0;
#pragma unroll
        for (int mi = 0; mi < 4; mi++)
#pragma unroll
            for (int ni = 0; ni < 4; ni++) {
                int col = n0 + wn + ni * 16 + l15;
                float bc = bias[col];
#pragma unroll
                for (int r = 0; r < 4; r++) {
                    size_t row = m0 + wm + mi * 16 + quad * 4 + r;
                    C[row * (size_t)ldc + col] = acc[mi][ni][r] + bc;
                }
            }
    } else {
        if (n0 < 768) {
            bf16_t* qkc = (bf16_t*)C0;
#pragma unroll
            for (int mi = 0; mi < 4; mi++)
#pragma unroll
                for (int ni = 0; ni < 4; ni++) {
                    int col = n0 + wn + ni * 16 + l15;
                    float bc = bias[col];
#pragma unroll
                    for (int r = 0; r < 4; r++) {
                        size_t row = m0 + wm + mi * 16 + quad * 4 + r;
                        qkc[row * 768 + col] = (bf16_t)(acc[mi][ni][r] + bc);
                    }
                }
        } else {
            // V^T store: vt[b][vcol][s], b=row/49, s=row%49
#pragma unroll
            for (int mi = 0; mi < 4; mi++)
#pragma unroll
                for (int ni = 0; ni < 4; ni++) {
                    int col = n0 + wn + ni * 16 + l15;
                    float bc = bias[col];
                    int vcol = col - 768;
#pragma unroll
                    for (int r = 0; r < 4; r++) {
                        uint32_t row = (uint32_t)(m0 + wm + mi * 16 + quad * 4 + r);
                        uint32_t b = row / 49u;
                        uint32_t s = row - b * 49u;
                        vt[((size_t)b * 384 + vcol) * 64 + s] =
                            (bf16_t)(acc[mi][ni][r] + bc);
                    }
                }
            // zero the s=49..63 padding for windows this slab touches
            // (idempotent across slabs; attn reads full s 0..63)
            int b0 = (int)(m0 / 49);
#pragma unroll 1
            for (int bw = 0; bw < 4; ++bw) {
                int b = b0 + bw;
                if (b < NWIN && b * 49 < (int)(m0) + 128) {
#pragma unroll 1
                    for (int e = tid; e < 128 * 15; e += 256) {
                        int cl = e / 15;
                        int sp = 49 + (e - cl * 15);
                        vt[((size_t)b * 384 + (n0 - 768) + cl) * 64 + sp] = (bf16_t)0.f;
                    }
                }
            }
        }
    }
}

// ---------------------------------------------------------------------------
// Kernel 3: fused window attention. One wave = one (window, head).
// qk[row][768]: q cols h*32, k cols 384+h*32. vt[b][h*32+d][s64] (V^T, padded).
// No __syncthreads; per-wave P scratch in LDS. Grid 12288, XCD-chunk swizzle.
// ---------------------------------------------------------------------------
__global__ __launch_bounds__(256, 4) void attn_kernel(
    const bf16_t* __restrict__ qk, const bf16_t* __restrict__ vt,
    const float* __restrict__ bias_l, bf16_t* __restrict__ aout) {
    // per-wave P scratch: 64 rows x stride 72 elems (16B-aligned b128 reads,
    // 2-way bank aliasing = free)
    __shared__ bf16_t Ps[4][64 * 72];

    const int lane = threadIdx.x & 63;
    const int wave = threadIdx.x >> 6;
    const int l15  = lane & 15;
    const int quad = lane >> 4;
    const int bid  = blockIdx.x;
    const int wid  = (bid & 7) * ((NWIN * NHEADS / 4) / 8) + (bid >> 3);
    const int gw   = wid * 4 + wave;          // 0..49151
    const int b    = gw / NHEADS;
    const int h    = gw - b * NHEADS;

    const bf16_t* qb = qk + (size_t)b * SEQ * 768 + h * HEADD;
    const bf16_t* kb = qb + DIM_C;
    const bf16_t* vb = vt + ((size_t)b * 384 + h * HEADD) * 64;
    const float*  bh = bias_l + h * 4096;
    bf16_t* ps = &Ps[wave][0];

    // ---- Q/K fragments straight from global (A/B frag = 8 contiguous k) ----
    bf16x8 qf[4], kf[4];
#pragma unroll
    for (int mi = 0; mi < 4; mi++) {
        int row = mi * 16 + l15;
        if (row < SEQ) {
            qf[mi] = *(const bf16x8*)(qb + (size_t)row * 768 + quad * 8);
            kf[mi] = *(const bf16x8*)(kb + (size_t)row * 768 + quad * 8);
        } else {
            bf16x8 z;
#pragma unroll
            for (int j = 0; j < 8; j++) z[j] = (bf16_t)0.f;
            qf[mi] = z; kf[mi] = z;
        }
    }
    // ---- S = Q K^T (64x64 padded) ----
    f32x4 S[4][4];
#pragma unroll
    for (int mi = 0; mi < 4; mi++)
#pragma unroll
        for (int ni = 0; ni < 4; ni++)
            S[mi][ni] = __builtin_amdgcn_mfma_f32_16x16x32_bf16(
                qf[mi], kf[ni], f32x4{0.f, 0.f, 0.f, 0.f}, 0, 0, 0);
    // ---- scale + bias (mask folded into bias_l padding) + row softmax ----
    // C layout: m = mi*16+quad*4+r, n = ni*16+l15; bias_l gives lane's 4 n as float4
#pragma unroll
    for (int mi = 0; mi < 4; mi++)
#pragma unroll
        for (int r = 0; r < 4; r++) {
            int m = mi * 16 + quad * 4 + r;
            f32x4 bv = *(const f32x4*)(bh + ((m << 4) + l15) * 4);
            float mx = -1e30f;
#pragma unroll
            for (int ni = 0; ni < 4; ni++) {
                float s = S[mi][ni][r] * ATTN_SCALE + bv[ni];
                S[mi][ni][r] = s;
                mx = fmaxf(mx, s);
            }
#pragma unroll
            for (int off = 1; off < 16; off <<= 1)
                mx = fmaxf(mx, __shfl_xor(mx, off, 64));
            float sum = 0.f;
#pragma unroll
            for (int ni = 0; ni < 4; ni++) {
                float e = __expf(S[mi][ni][r] - mx);
                S[mi][ni][r] = e;
                sum += e;
            }
#pragma unroll
            for (int off = 1; off < 16; off <<= 1)
                sum += __shfl_xor(sum, off, 64);
            float inv = 1.f / sum;
#pragma unroll
            for (int ni = 0; ni < 4; ni++) {
                int n = ni * 16 + l15;
                ps[m * 72 + n] = (bf16_t)(S[mi][ni][r] * inv);
            }
        }
    // ---- V fragments: clean vector loads from pre-transposed V^T ----
    bf16x8 vf[2][2];
#pragma unroll
    for (int ki = 0; ki < 2; ki++)
#pragma unroll
        for (int di = 0; di < 2; di++)
            vf[ki][di] = *(const bf16x8*)(vb + (size_t)(di * 16 + l15) * 64 + ki * 32 + quad * 8);
    // ---- O = P V  (P A-frags from LDS; same-wave ordering via lgkmcnt) ----
    f32x4 O[4][2];
#pragma unroll
    for (int mi = 0; mi < 4; mi++)
#pragma unroll
        for (int di = 0; di < 2; di++) O[mi][di] = f32x4{0.f, 0.f, 0.f, 0.f};
#pragma unroll
    for (int mi = 0; mi < 4; mi++)
#pragma unroll
        for (int ki = 0; ki < 2; ki++) {
            bf16x8 pa = *(const bf16x8*)(ps + (mi * 16 + l15) * 72 + ki * 32 + quad * 8);
#pragma unroll
            for (int di = 0; di < 2; di++)
                O[mi][di] = __builtin_amdgcn_mfma_f32_16x16x32_bf16(
                    pa, vf[ki][di], O[mi][di], 0, 0, 0);
        }
    // ---- store O rows m<49, layout [b*49+m, h*32+d] ----
#pragma unroll
    for (int mi = 0; mi < 4; mi++)
#pragma unroll
        for (int di = 0; di < 2; di++)
#pragma unroll
            for (int r = 0; r < 4; r++) {
                int m = mi * 16 + quad * 4 + r;
                if (m < SEQ)
                    aout[((size_t)b * SEQ + m) * DIM_C + h * HEADD + di * 16 + l15] =
                        (bf16_t)O[mi][di][r];
            }
}

// ---------------------------------------------------------------------------
extern "C" void kernel_launch(void* const* d_in, const int* in_sizes, int n_in,
                              void* d_out, int out_size, void* d_ws, size_t ws_size,
                              hipStream_t stream) {
    (void)in_sizes; (void)n_in; (void)out_size; (void)ws_size;
    const float* x      = (const float*)d_in[0];
    const float* qkv_w  = (const float*)d_in[1];
    const float* qkv_b  = (const float*)d_in[2];
    const float* proj_w = (const float*)d_in[3];
    const float* proj_b = (const float*)d_in[4];
    const float* btable = (const float*)d_in[5];
    const int*   rel    = (const int*)d_in[6];
    float* out = (float*)d_out;

    char* ws = (char*)d_ws;
    bf16_t* qkbuf     = (bf16_t*)ws;
    bf16_t* aout      = (bf16_t*)(ws + QK_BYTES);
    float*  bias_l    = (float*)(ws + QK_BYTES + AOUT_BYTES);
    bf16_t* qkv_w_bf  = (bf16_t*)(ws + QK_BYTES + AOUT_BYTES + BIASL_BYTES);
    bf16_t* proj_w_bf = (bf16_t*)(ws + QK_BYTES + AOUT_BYTES + BIASL_BYTES + QKVW_BF_BYTES);
    // V^T scratch lives in d_out (308MB >= 201MB); dead by the time proj writes out.
    bf16_t* vt        = (bf16_t*)d_out;

    // one-time small preprocessing
    convert_f32_bf16_kernel<<<(QKV_N * DIM_C / 4 + 255) / 256, 256, 0, stream>>>(
        qkv_w, qkv_w_bf, QKV_N * DIM_C / 4);
    convert_f32_bf16_kernel<<<(DIM_C * DIM_C / 4 + 255) / 256, 256, 0, stream>>>(
        proj_w, proj_w_bf, DIM_C * DIM_C / 4);
    bias_expand_kernel<<<(NHEADS * 64 * 64 + 255) / 256, 256, 0, stream>>>(
        btable, rel, bias_l);

    // QKV GEMM (split output): nwg = 1568*9 = 14112 (%8==0, chunk 1764 = 196*9)
    gemm_kernel<false, 1, QKV_N / 128><<<(MTOT / 128) * (QKV_N / 128), 256, 0, stream>>>(
        x, qkv_w_bf, qkv_b, qkbuf, vt, 0);
    // attention: 12288 blocks (%8==0, chunk 1536 = 512*3 windows intact)
    attn_kernel<<<NWIN * NHEADS / 4, 256, 0, stream>>>(qkbuf, vt, bias_l, aout);
    // proj GEMM: nwg = 1568*3 = 4704 (%8==0, chunk 588 = 196*3)
    gemm_kernel<true, 0, DIM_C / 128><<<(MTOT / 128) * (DIM_C / 128), 256, 0, stream>>>(
        aout, proj_w_bf, proj_b, out, nullptr, DIM_C);
}